// Round 1
// baseline (191.154 us; speedup 1.0000x reference)
//
#include <hip/hip_runtime.h>
#include <hip/hip_bf16.h>

// z_{k+1} = tanh(z_k @ W^T + b + x), z_0 = 0, 25 iterations.
// Rows are independent => each workgroup iterates its 32 rows to completion.
// W held in registers as MFMA A-operand (bf16), z^T staged in LDS (bf16,
// double-buffered) as B-operand, fp32 accumulate, x+b preloaded into
// C-fragment-layout registers. 16x16x32 bf16 MFMA.

#define BATCH   32768
#define FEAT    256
#define ROWS_WG 32
#define SROW    264   // 256 + 8 bf16 pad -> conflict-free ds_read_b128
#define NITER   25

typedef __bf16 bf16x8 __attribute__((ext_vector_type(8)));
typedef float  f32x4  __attribute__((ext_vector_type(4)));

static __device__ __forceinline__ unsigned short f2bf(float f) {
    unsigned u = __builtin_bit_cast(unsigned, f);
    u += 0x7fffu + ((u >> 16) & 1u);          // RNE (no NaN in this problem)
    return (unsigned short)(u >> 16);
}

static __device__ __forceinline__ unsigned pack2(float a, float b) {
    return (unsigned)f2bf(a) | ((unsigned)f2bf(b) << 16);
}

// tanh(h) = 1 - 2/(exp(2h)+1), exp(2h) = exp2(h * 2*log2(e))
static __device__ __forceinline__ float tanh_fast(float h) {
    float e = __builtin_amdgcn_exp2f(h * 2.8853900817779268f);
    float r = __builtin_amdgcn_rcpf(e + 1.0f);
    return __builtin_fmaf(-2.0f, r, 1.0f);
}

__global__ __launch_bounds__(256, 2)
void IterativeFixedPoint_kernel(const float* __restrict__ X,
                                const float* __restrict__ W,
                                const float* __restrict__ Bv,
                                float* __restrict__ Out)
{
    __shared__ unsigned short zsh[2][ROWS_WG][SROW];

    const int tid  = threadIdx.x;
    const int wv   = tid >> 6;        // wave id, owns output cols [64*wv, 64*wv+64)
    const int lane = tid & 63;
    const int c    = lane & 15;       // batch-row within tile (N dim of MFMA)
    const int q    = lane >> 4;       // quad id
    const int j0   = wv * 64;
    const int row0 = blockIdx.x * ROWS_WG;

    // ---- Load W fragments (A operand), once. A[m=c][k=q*8+t] per tile. ----
    bf16x8 wf[4][8];
#pragma unroll
    for (int jt = 0; jt < 4; ++jt) {
        const float* wr = W + (unsigned)(j0 + jt * 16 + c) * FEAT;
#pragma unroll
        for (int ks = 0; ks < 8; ++ks) {
            const f32x4* p4 = (const f32x4*)(wr + ks * 32 + q * 8);
            f32x4 a = p4[0];
            f32x4 b = p4[1];
            union { bf16x8 v; unsigned u[4]; } t;
            t.u[0] = pack2(a[0], a[1]);
            t.u[1] = pack2(a[2], a[3]);
            t.u[2] = pack2(b[0], b[1]);
            t.u[3] = pack2(b[2], b[3]);
            wf[jt][ks] = t.v;
        }
    }

    // ---- x + b in C-fragment layout: element r -> (i=row0+it*16+c, j=j0+jt*16+q*4+r)
    f32x4 xb[2][4];
#pragma unroll
    for (int it = 0; it < 2; ++it) {
        const float* xr = X + (unsigned)(row0 + it * 16 + c) * FEAT + j0;
#pragma unroll
        for (int jt = 0; jt < 4; ++jt) {
            f32x4 xv = *(const f32x4*)(xr + jt * 16 + q * 4);
            f32x4 bv = *(const f32x4*)(Bv + j0 + jt * 16 + q * 4);
            xb[it][jt] = xv + bv;
        }
    }

    // ---- Iteration 1: z1 = tanh(x + b)  (W @ 0 = 0) ----
#pragma unroll
    for (int it = 0; it < 2; ++it) {
#pragma unroll
        for (int jt = 0; jt < 4; ++jt) {
            f32x4 h = xb[it][jt];
            float t0 = tanh_fast(h[0]);
            float t1 = tanh_fast(h[1]);
            float t2 = tanh_fast(h[2]);
            float t3 = tanh_fast(h[3]);
            uint2 pk;
            pk.x = pack2(t0, t1);
            pk.y = pack2(t2, t3);
            *(uint2*)(&zsh[0][it * 16 + c][j0 + jt * 16 + q * 4]) = pk;
        }
    }
    __syncthreads();

    // ---- Iterations 2..24: MFMA + tanh, LDS double-buffer ----
    int p = 0;
    for (int iter = 0; iter < NITER - 2; ++iter) {
#pragma unroll
        for (int it = 0; it < 2; ++it) {
            const unsigned short* zr = &zsh[p][it * 16 + c][0];
            bf16x8 zf[8];
#pragma unroll
            for (int ks = 0; ks < 8; ++ks)
                zf[ks] = *(const bf16x8*)(zr + ks * 32 + q * 8);
            f32x4 acc[4];
#pragma unroll
            for (int jt = 0; jt < 4; ++jt) acc[jt] = xb[it][jt];
#pragma unroll
            for (int ks = 0; ks < 8; ++ks)
#pragma unroll
                for (int jt = 0; jt < 4; ++jt)
                    acc[jt] = __builtin_amdgcn_mfma_f32_16x16x32_bf16(
                        wf[jt][ks], zf[ks], acc[jt], 0, 0, 0);
#pragma unroll
            for (int jt = 0; jt < 4; ++jt) {
                float t0 = tanh_fast(acc[jt][0]);
                float t1 = tanh_fast(acc[jt][1]);
                float t2 = tanh_fast(acc[jt][2]);
                float t3 = tanh_fast(acc[jt][3]);
                uint2 pk;
                pk.x = pack2(t0, t1);
                pk.y = pack2(t2, t3);
                *(uint2*)(&zsh[p ^ 1][it * 16 + c][j0 + jt * 16 + q * 4]) = pk;
            }
        }
        p ^= 1;
        __syncthreads();
    }

    // ---- Final iteration (25): store fp32 tanh directly to global ----
#pragma unroll
    for (int it = 0; it < 2; ++it) {
        const unsigned short* zr = &zsh[p][it * 16 + c][0];
        bf16x8 zf[8];
#pragma unroll
        for (int ks = 0; ks < 8; ++ks)
            zf[ks] = *(const bf16x8*)(zr + ks * 32 + q * 8);
        f32x4 acc[4];
#pragma unroll
        for (int jt = 0; jt < 4; ++jt) acc[jt] = xb[it][jt];
#pragma unroll
        for (int ks = 0; ks < 8; ++ks)
#pragma unroll
            for (int jt = 0; jt < 4; ++jt)
                acc[jt] = __builtin_amdgcn_mfma_f32_16x16x32_bf16(
                    wf[jt][ks], zf[ks], acc[jt], 0, 0, 0);
#pragma unroll
        for (int jt = 0; jt < 4; ++jt) {
            f32x4 o;
            o[0] = tanh_fast(acc[jt][0]);
            o[1] = tanh_fast(acc[jt][1]);
            o[2] = tanh_fast(acc[jt][2]);
            o[3] = tanh_fast(acc[jt][3]);
            *(f32x4*)(Out + (unsigned)(row0 + it * 16 + c) * FEAT +
                      j0 + jt * 16 + q * 4) = o;
        }
    }
}

extern "C" void kernel_launch(void* const* d_in, const int* in_sizes, int n_in,
                              void* d_out, int out_size, void* d_ws, size_t ws_size,
                              hipStream_t stream) {
    (void)in_sizes; (void)n_in; (void)d_ws; (void)ws_size; (void)out_size;
    const float* X  = (const float*)d_in[0];
    const float* W  = (const float*)d_in[1];
    const float* Bv = (const float*)d_in[2];
    float* Out = (float*)d_out;
    IterativeFixedPoint_kernel<<<dim3(BATCH / ROWS_WG), dim3(256), 0, stream>>>(
        X, W, Bv, Out);
}

// Round 3
// 179.590 us; speedup vs baseline: 1.0644x; 1.0644x over previous
//
#include <hip/hip_runtime.h>
#include <hip/hip_bf16.h>

// z_{k+1} = tanh(z_k @ W^T + b + x), z_0 = 0, 25 iterations, rows independent.
// Sigmoid reformulation: y = sigma(2h), z = 2y-1  =>
//   h' = 2*W*y + (x + b - rowsum(W))
// Pre-scale so the MFMA output S feeds exp2 directly:
//   W'' = 4*log2(e)*W  (fp16, A-operand, register-resident)
//   xb  = 2*log2(e)*(x + b - rowsum(W))  (fp32, C-fragment layout)
//   y'  = rcp(1 + exp2(-S))          [3 VALU ops, -S via free src modifier]
// y staged in LDS (fp16, double-buffered) as B-operand; fp32 accumulate.
// Final iter: z = 2*y - 1 in fp32, stored directly.

#define BATCH   32768
#define FEAT    256
#define ROWS_WG 32
#define SROW    264   // 256 + 8 halfwords pad
#define NITER   25

typedef _Float16 f16x8 __attribute__((ext_vector_type(8)));
typedef __fp16   h16x2 __attribute__((ext_vector_type(2)));
typedef float    f32x4 __attribute__((ext_vector_type(4)));

#define K4 5.7707801635558535f   // 4*log2(e)
#define K2 2.8853900817779268f   // 2*log2(e)

static __device__ __forceinline__ unsigned pkh(float a, float b) {
    h16x2 h = __builtin_amdgcn_cvt_pkrtz(a, b);
    return __builtin_bit_cast(unsigned, h);
}

// y = 1/(1 + 2^-s)
static __device__ __forceinline__ float sig_fast(float s) {
    float e = __builtin_amdgcn_exp2f(-s);
    return __builtin_amdgcn_rcpf(e + 1.0f);
}

__global__ __launch_bounds__(256, 2)
void IterativeFixedPoint_kernel(const float* __restrict__ X,
                                const float* __restrict__ W,
                                const float* __restrict__ Bv,
                                float* __restrict__ Out)
{
    __shared__ unsigned short zsh[2][ROWS_WG][SROW];

    const int tid  = threadIdx.x;
    const int wv   = tid >> 6;
    const int lane = tid & 63;
    const int c    = lane & 15;       // batch-row within 16-tile / W output row
    const int q    = lane >> 4;       // quad id
    const int j0   = wv * 64;
    const int row0 = blockIdx.x * ROWS_WG;

    // ---- Load W (A operand) once: scale by K4, convert fp16; raw fp32 rowsum.
    f16x8 wf[4][8];
    float ps[4];
#pragma unroll
    for (int jt = 0; jt < 4; ++jt) {
        const float* wr = W + (unsigned)(j0 + jt * 16 + c) * FEAT;
        float s = 0.0f;
#pragma unroll
        for (int ks = 0; ks < 8; ++ks) {
            const f32x4* p4 = (const f32x4*)(wr + ks * 32 + q * 8);
            f32x4 a = p4[0];
            f32x4 b = p4[1];
            s += ((a[0] + a[1]) + (a[2] + a[3])) + ((b[0] + b[1]) + (b[2] + b[3]));
            union { f16x8 v; unsigned u[4]; } t;
            t.u[0] = pkh(a[0] * K4, a[1] * K4);
            t.u[1] = pkh(a[2] * K4, a[3] * K4);
            t.u[2] = pkh(b[0] * K4, b[1] * K4);
            t.u[3] = pkh(b[2] * K4, b[3] * K4);
            wf[jt][ks] = t.v;
        }
        ps[jt] = s;
    }

    // ---- rowsum(W) per output row, then redistribute to C-fragment layout.
    f32x4 rsv[4];
#pragma unroll
    for (int jt = 0; jt < 4; ++jt) {
        float s = ps[jt];
        s += __shfl_xor(s, 16);
        s += __shfl_xor(s, 32);       // s = rowsum of W row (j0 + jt*16 + c)
        ps[jt] = s;
    }
#pragma unroll
    for (int jt = 0; jt < 4; ++jt) {
        f32x4 v;
#pragma unroll
        for (int r = 0; r < 4; ++r)
            v[r] = __shfl(ps[jt], q * 4 + r);   // rowsum of row jt*16+q*4+r
        rsv[jt] = v;
    }

    // ---- xb = K2*(x + b - rowsum)  in C-fragment layout.
    f32x4 xb[2][4];
#pragma unroll
    for (int it = 0; it < 2; ++it) {
        const float* xr = X + (unsigned)(row0 + it * 16 + c) * FEAT + j0;
#pragma unroll
        for (int jt = 0; jt < 4; ++jt) {
            f32x4 xv = *(const f32x4*)(xr + jt * 16 + q * 4);
            f32x4 bv = *(const f32x4*)(Bv + j0 + jt * 16 + q * 4);
            xb[it][jt] = (xv + bv - rsv[jt]) * K2;
        }
    }

    // ---- Iteration 1: S1 = K2*(x+b) = xb + K2*rowsum;  y1 = sigma(S1).
#pragma unroll
    for (int it = 0; it < 2; ++it) {
#pragma unroll
        for (int jt = 0; jt < 4; ++jt) {
            f32x4 S = xb[it][jt] + K2 * rsv[jt];
            uint2 pk;
            pk.x = pkh(sig_fast(S[0]), sig_fast(S[1]));
            pk.y = pkh(sig_fast(S[2]), sig_fast(S[3]));
            *(uint2*)(&zsh[0][it * 16 + c][j0 + jt * 16 + q * 4]) = pk;
        }
    }
    __syncthreads();

    // ---- Iterations 2..24: MFMA + sigmoid, LDS double-buffer.
    int p = 0;
    for (int iter = 0; iter < NITER - 2; ++iter) {
#pragma unroll
        for (int it = 0; it < 2; ++it) {
            const unsigned short* zr = &zsh[p][it * 16 + c][0];
            f16x8 zf[8];
#pragma unroll
            for (int ks = 0; ks < 8; ++ks)
                zf[ks] = *(const f16x8*)(zr + ks * 32 + q * 8);
            f32x4 acc[4];
#pragma unroll
            for (int jt = 0; jt < 4; ++jt)
                acc[jt] = __builtin_amdgcn_mfma_f32_16x16x32_f16(
                    wf[jt][0], zf[0], xb[it][jt], 0, 0, 0);
#pragma unroll
            for (int ks = 1; ks < 8; ++ks)
#pragma unroll
                for (int jt = 0; jt < 4; ++jt)
                    acc[jt] = __builtin_amdgcn_mfma_f32_16x16x32_f16(
                        wf[jt][ks], zf[ks], acc[jt], 0, 0, 0);
#pragma unroll
            for (int jt = 0; jt < 4; ++jt) {
                uint2 pk;
                pk.x = pkh(sig_fast(acc[jt][0]), sig_fast(acc[jt][1]));
                pk.y = pkh(sig_fast(acc[jt][2]), sig_fast(acc[jt][3]));
                *(uint2*)(&zsh[p ^ 1][it * 16 + c][j0 + jt * 16 + q * 4]) = pk;
            }
        }
        p ^= 1;
        __syncthreads();
    }

    // ---- Final iteration (25): z = 2*y - 1 in fp32, store to global.
#pragma unroll
    for (int it = 0; it < 2; ++it) {
        const unsigned short* zr = &zsh[p][it * 16 + c][0];
        f16x8 zf[8];
#pragma unroll
        for (int ks = 0; ks < 8; ++ks)
            zf[ks] = *(const f16x8*)(zr + ks * 32 + q * 8);
        f32x4 acc[4];
#pragma unroll
        for (int jt = 0; jt < 4; ++jt)
            acc[jt] = __builtin_amdgcn_mfma_f32_16x16x32_f16(
                wf[jt][0], zf[0], xb[it][jt], 0, 0, 0);
#pragma unroll
        for (int ks = 1; ks < 8; ++ks)
#pragma unroll
            for (int jt = 0; jt < 4; ++jt)
                acc[jt] = __builtin_amdgcn_mfma_f32_16x16x32_f16(
                    wf[jt][ks], zf[ks], acc[jt], 0, 0, 0);
#pragma unroll
        for (int jt = 0; jt < 4; ++jt) {
            f32x4 o;
#pragma unroll
            for (int r = 0; r < 4; ++r)
                o[r] = __builtin_fmaf(2.0f, sig_fast(acc[jt][r]), -1.0f);
            *(f32x4*)(Out + (unsigned)(row0 + it * 16 + c) * FEAT +
                      j0 + jt * 16 + q * 4) = o;
        }
    }
}

extern "C" void kernel_launch(void* const* d_in, const int* in_sizes, int n_in,
                              void* d_out, int out_size, void* d_ws, size_t ws_size,
                              hipStream_t stream) {
    (void)in_sizes; (void)n_in; (void)d_ws; (void)ws_size; (void)out_size;
    const float* X  = (const float*)d_in[0];
    const float* W  = (const float*)d_in[1];
    const float* Bv = (const float*)d_in[2];
    float* Out = (float*)d_out;
    IterativeFixedPoint_kernel<<<dim3(BATCH / ROWS_WG), dim3(256), 0, stream>>>(
        X, W, Bv, Out);
}